// Round 10
// baseline (692.908 us; speedup 1.0000x reference)
//
#include <hip/hip_runtime.h>
#include <hip/hip_bf16.h>

#define IN_DIM 128
#define PE_DIM 16
#define F_IN 144      // IN+PE
#define HID 128
#define LAT 64
#define K_CHEB 4

typedef unsigned int uint;
typedef unsigned short ushort;
typedef unsigned char uchar;
typedef unsigned long long ull;
typedef __attribute__((ext_vector_type(8))) short short8;
typedef __attribute__((ext_vector_type(4))) float floatx4;
typedef __attribute__((ext_vector_type(2))) float floatx2;

// ---------------------------------------------------------------- bf16 helpers
__device__ __forceinline__ ushort f2bf(float f) {
    uint u = __float_as_uint(f);
    uint r = (u + 0x7FFFu + ((u >> 16) & 1u)) >> 16;   // RNE
    return (ushort)r;
}
__device__ __forceinline__ uint bf_pack(float lo, float hi) {
    return (uint)f2bf(lo) | ((uint)f2bf(hi) << 16);
}

// ---------------------------------------------------------------- fp8 helpers (OCP e4m3 on gfx950)
template<bool HI>
__device__ __forceinline__ floatx2 fp8x2_f32(uint v) {
    return __builtin_amdgcn_cvt_pk_f32_fp8((int)v, HI);
}
template<bool HI>
__device__ __forceinline__ uint f32_fp8x2(float a, float b, uint old) {
    return (uint)__builtin_amdgcn_cvt_pk_fp8_f32(a, b, (int)old, HI);
}

// ---------------------------------------------------------------- non-temporal helpers
__device__ __forceinline__ uint2 ntload_u2(const uint2* p) {
    ull v = __builtin_nontemporal_load((const ull*)p);
    uint2 r; r.x = (uint)v; r.y = (uint)(v >> 32); return r;
}
__device__ __forceinline__ void ntstore_u2(uint2* p, uint2 v) {
    ull q = (ull)v.x | ((ull)v.y << 32);
    __builtin_nontemporal_store(q, (ull*)p);
}
__device__ __forceinline__ uint ntload_u(const uint* p) {
    return __builtin_nontemporal_load(p);
}
__device__ __forceinline__ void ntstore_u(uint* p, uint v) {
    __builtin_nontemporal_store(v, p);
}

// ---------------------------------------------------------------- utility
__global__ void zero_kernel(float* __restrict__ p, size_t n) {
    size_t i = (size_t)blockIdx.x * 256 + threadIdx.x;
    if (i < n) p[i] = 0.f;
}

// ================================================================ graph prep
// 512-node buckets; NBUCK = ceil(N/512) <= 256.

__global__ __launch_bounds__(256) void bin_hist(const int* __restrict__ ei,
                                                int* __restrict__ ghA,
                                                int* __restrict__ ghB, int E) {
    __shared__ int hA[256], hB[256];
    int t = threadIdx.x;
    hA[t] = 0; hB[t] = 0;
    __syncthreads();
    int base = blockIdx.x * 4096;
#pragma unroll
    for (int j = 0; j < 16; j++) {
        int e = base + t + j * 256;
        if (e < E) {
            int s = ei[e], d = ei[E + e];
            atomicAdd(&hA[s >> 9], 1);
            atomicAdd(&hB[d >> 9], 1);
        }
    }
    __syncthreads();
    atomicAdd(&ghA[t], hA[t]);
    atomicAdd(&ghB[t], hB[t]);
}

__global__ __launch_bounds__(256) void bin_scan(const int* __restrict__ ghA,
                                                const int* __restrict__ ghB,
                                                int* __restrict__ bbA, int* __restrict__ curA,
                                                int* __restrict__ bbB, int* __restrict__ curB) {
    __shared__ int s[256];
    int t = threadIdx.x;
    int v = ghA[t];
    s[t] = v; __syncthreads();
    for (int off = 1; off < 256; off <<= 1) {
        int u = (t >= off) ? s[t - off] : 0;
        __syncthreads(); s[t] += u; __syncthreads();
    }
    bbA[t] = s[t] - v; curA[t] = s[t] - v;
    if (t == 255) bbA[256] = s[255];
    __syncthreads();
    int v2 = ghB[t];
    s[t] = v2; __syncthreads();
    for (int off = 1; off < 256; off <<= 1) {
        int u = (t >= off) ? s[t - off] : 0;
        __syncthreads(); s[t] += u; __syncthreads();
    }
    bbB[t] = s[t] - v2; curB[t] = s[t] - v2;
    if (t == 255) bbB[256] = s[255];
}

// ---- dual scatter: one pass over edges builds BOTH bucket-grouped streams.
// A: key=src, rec=(src, w).  B: key=dst, rec=(src | dstLow<<17, w).
// 2048 edges/block; edge data cached in registers between phases.
__global__ __launch_bounds__(256) void bin_scatter2(const int* __restrict__ ei,
                                                    const float* __restrict__ ew,
                                                    int* __restrict__ curA,
                                                    int* __restrict__ curB,
                                                    uint2* __restrict__ sA,
                                                    uint2* __restrict__ sB, int E) {
    __shared__ uint2 recA[2048]; __shared__ int posA[2048];
    __shared__ uint2 recB[2048]; __shared__ int posB[2048];
    __shared__ int hstA[256], scnA[256], runA[256], bgA[256];
    __shared__ int hstB[256], scnB[256], runB[256], bgB[256];
    int t = threadIdx.x;
    hstA[t] = 0; hstB[t] = 0;
    __syncthreads();
    int base = blockIdx.x * 2048;
    int cntBlk = E - base; if (cntBlk > 2048) cntBlk = 2048;
    int sv[8], dv[8]; float wv[8];
#pragma unroll
    for (int j = 0; j < 8; j++) {
        int e = base + t + j * 256;
        if (e < E) {
            sv[j] = ei[e]; dv[j] = ei[E + e];
            wv[j] = (sv[j] == dv[j]) ? 0.f : ew[e];
            atomicAdd(&hstA[sv[j] >> 9], 1);
            atomicAdd(&hstB[dv[j] >> 9], 1);
        } else sv[j] = -1;
    }
    __syncthreads();
    // scan A
    int vA = hstA[t];
    scnA[t] = vA; __syncthreads();
    for (int off = 1; off < 256; off <<= 1) {
        int u = (t >= off) ? scnA[t - off] : 0;
        __syncthreads(); scnA[t] += u; __syncthreads();
    }
    int eA = scnA[t] - vA;
    bgA[t] = atomicAdd(&curA[t], vA);
    __syncthreads();
    scnA[t] = eA; runA[t] = eA;
    // scan B
    int vB = hstB[t];
    scnB[t] = vB; __syncthreads();
    for (int off = 1; off < 256; off <<= 1) {
        int u = (t >= off) ? scnB[t - off] : 0;
        __syncthreads(); scnB[t] += u; __syncthreads();
    }
    int eB = scnB[t] - vB;
    bgB[t] = atomicAdd(&curB[t], vB);
    __syncthreads();
    scnB[t] = eB; runB[t] = eB;
    __syncthreads();
#pragma unroll
    for (int j = 0; j < 8; j++) {
        if (sv[j] >= 0) {
            int bA = sv[j] >> 9;
            int slot = atomicAdd(&runA[bA], 1);
            uint2 r; r.x = (uint)sv[j]; r.y = __float_as_uint(wv[j]);
            recA[slot] = r;
            posA[slot] = bgA[bA] + (slot - scnA[bA]);
            int bB = dv[j] >> 9;
            int slot2 = atomicAdd(&runB[bB], 1);
            uint2 r2; r2.x = (uint)sv[j] | ((uint)(dv[j] & 511) << 17); r2.y = __float_as_uint(wv[j]);
            recB[slot2] = r2;
            posB[slot2] = bgB[bB] + (slot2 - scnB[bB]);
        }
    }
    __syncthreads();
    for (int i = t; i < cntBlk; i += 256) {
        ntstore_u2(&sA[posA[i]], recA[i]);
        ntstore_u2(&sB[posB[i]], recB[i]);
    }
}

__global__ __launch_bounds__(256) void deg_bucket(const uint2* __restrict__ sA,
                                                  const int* __restrict__ bbA,
                                                  float* __restrict__ dinv, int N) {
    __shared__ float dl[512];
    int b = blockIdx.x, t = threadIdx.x;
    dl[t] = 0.f; dl[t + 256] = 0.f;
    __syncthreads();
    int s0 = bbA[b], s1 = bbA[b + 1];
    for (int r = s0 + t; r < s1; r += 256) {
        uint2 rc = ntload_u2(&sA[r]);
        atomicAdd(&dl[(int)rc.x - (b << 9)], __uint_as_float(rc.y));
    }
    __syncthreads();
    for (int i = t; i < 512; i += 256) {
        int node = (b << 9) + i;
        if (node < N) {
            float d = dl[i];
            dinv[node] = (d > 0.f) ? rsqrtf(d) : 0.f;
        }
    }
}

__global__ __launch_bounds__(256) void csr_bucket(const uint2* __restrict__ sB,
                                                  const int* __restrict__ bbB,
                                                  const float* __restrict__ dinv,
                                                  int* __restrict__ rowp,
                                                  uint2* __restrict__ csr,
                                                  int N, int nbuck, int E) {
    __shared__ int cl[512], ol[512], orun[512];
    __shared__ float dvl[512];
    __shared__ int ps[256];
    int b = blockIdx.x, t = threadIdx.x;
    cl[t] = 0; cl[t + 256] = 0;
    for (int i = t; i < 512; i += 256) {
        int node = (b << 9) + i;
        dvl[i] = (node < N) ? dinv[node] : 0.f;
    }
    __syncthreads();
    int s0 = bbB[b], s1 = bbB[b + 1];
    for (int r = s0 + t; r < s1; r += 256)
        atomicAdd(&cl[(sB[r].x >> 17) & 511], 1);
    __syncthreads();
    int v0 = cl[2 * t], v1 = cl[2 * t + 1];
    int pv = v0 + v1;
    ps[t] = pv; __syncthreads();
    for (int off = 1; off < 256; off <<= 1) {
        int u = (t >= off) ? ps[t - off] : 0;
        __syncthreads(); ps[t] += u; __syncthreads();
    }
    int pexcl = ps[t] - pv;
    ol[2 * t] = pexcl;       ol[2 * t + 1] = pexcl + v0;
    orun[2 * t] = pexcl;     orun[2 * t + 1] = pexcl + v0;
    {
        int n0 = (b << 9) + 2 * t;
        if (n0 < N)     rowp[n0] = s0 + ol[2 * t];
        if (n0 + 1 < N) rowp[n0 + 1] = s0 + ol[2 * t + 1];
    }
    if (b == nbuck - 1 && t == 0) rowp[N] = E;
    __syncthreads();
    for (int r = s0 + t; r < s1; r += 256) {
        uint2 rc = sB[r];
        int src = rc.x & 0x1FFFF;
        int dl_ = (rc.x >> 17) & 511;
        float w = __uint_as_float(rc.y);
        int rank = atomicAdd(&orun[dl_], 1);
        float wh = -dinv[src] * w * dvl[dl_];
        uint2 o; o.x = (uint)src; o.y = __float_as_uint(wh);
        ntstore_u2(&csr[s0 + rank], o);
    }
}

// ---------------------------------------------------------------- concat -> fp8 T1 slice 0
// T1 row = 4 slices x 144 fp8 = 576 B = 144 uints; slice0 uints [0,36)
__global__ void concat_x_fp8(const float* __restrict__ x, uint* __restrict__ T, size_t np) {
    size_t idx = (size_t)blockIdx.x * 256 + threadIdx.x;
    if (idx >= np) return;
    size_t i = idx >> 5; int p = (int)(idx & 31);
    float4 v = *(const float4*)(x + i * 128 + p * 4);
    uint o = f32_fp8x2<false>(v.x, v.y, 0u);
    o = f32_fp8x2<true>(v.z, v.w, o);
    T[i * 144 + p] = o;
}
__global__ void concat_pe_fp8(const float* __restrict__ pe, uint* __restrict__ T, size_t np) {
    size_t idx = (size_t)blockIdx.x * 256 + threadIdx.x;
    if (idx >= np) return;
    size_t i = idx >> 2; int p = (int)(idx & 3);
    float4 v = *(const float4*)(pe + i * 16 + p * 4);
    uint o = f32_fp8x2<false>(v.x, v.y, 0u);
    o = f32_fp8x2<true>(v.z, v.w, o);
    T[i * 144 + 32 + p] = o;
}

// ---------------------------------------------------------------- W -> Bt bf16 transpose (weights stay bf16)
template<int K>
__global__ void wconv_kernel(const float* __restrict__ W, ushort* __restrict__ Bt) {
    int idx = blockIdx.x * 256 + threadIdx.x;
    if (idx >= 128 * K) return;
    int n = idx / K, kk = idx - n * K;
    Bt[idx] = f2bf(W[(size_t)kk * 128 + n]);
}

// ---------------------------------------------------------------- propagate (fp8 tables, fp32 accum)
// One wave per node; 4 edge-groups x 16 lanes; 16 edges per iteration, uint2
// (8 fp8) per lane per edge. Streaming accesses (csr, told, output) use
// non-temporal hints so the gather table keeps L2 residency.
template<int F, int P>
__global__ __launch_bounds__(256) void prop_fp8(const uint* __restrict__ T,
                                                int off_src, int off_dst, int off_old,
                                                int recur,
                                                const int* __restrict__ rowp,
                                                const uint2* __restrict__ csrE, int n) {
    int node = blockIdx.x * 4 + (threadIdx.x >> 6);
    if (node >= n) return;
    int lane = threadIdx.x & 63;
    int g = lane >> 4;          // edge sub-group 0..3
    int ll = lane & 15;         // lane within group
    int e0 = rowp[node], e1 = rowp[node + 1];

    const uint* Tsrc = T + off_src;

    float acc[8];
#pragma unroll
    for (int i = 0; i < 8; i++) acc[i] = 0.f;
    float ex[4] = {0.f, 0.f, 0.f, 0.f};

    for (int base = e0; base < e1; base += 64) {
        int degc = e1 - base; if (degc > 64) degc = 64;
        int sidx = 0; float wval = 0.f;
        if (lane < degc) {
            uint2 rc = ntload_u2(&csrE[base + lane]);
            sidx = (int)rc.x; wval = __uint_as_float(rc.y);
        }
        for (int j = 0; j < degc; j += 16) {
            int j0 = j + g, j1 = j0 + 4, j2 = j0 + 8, j3 = j0 + 12;
            int   s0 = __shfl(sidx, j0), s1 = __shfl(sidx, j1);
            int   s2 = __shfl(sidx, j2), s3 = __shfl(sidx, j3);
            float w0 = __shfl(wval, j0), w1 = __shfl(wval, j1);
            float w2 = __shfl(wval, j2), w3 = __shfl(wval, j3);
            const uint* hp0 = Tsrc + (size_t)s0 * P;
            const uint* hp1 = Tsrc + (size_t)s1 * P;
            const uint* hp2 = Tsrc + (size_t)s2 * P;
            const uint* hp3 = Tsrc + (size_t)s3 * P;
            uint2 v0 = *(const uint2*)(hp0 + ll * 2);
            uint2 v1 = *(const uint2*)(hp1 + ll * 2);
            uint2 v2 = *(const uint2*)(hp2 + ll * 2);
            uint2 v3 = *(const uint2*)(hp3 + ll * 2);
            uint x0 = 0, x1 = 0, x2 = 0, x3 = 0;
            if (F == 144) {
                if (ll < 4) {
                    x0 = hp0[32 + ll]; x1 = hp1[32 + ll];
                    x2 = hp2[32 + ll]; x3 = hp3[32 + ll];
                }
            }
#define ACC8(v, w) { \
            floatx2 f0 = fp8x2_f32<false>(v.x), f1 = fp8x2_f32<true>(v.x); \
            floatx2 f2 = fp8x2_f32<false>(v.y), f3 = fp8x2_f32<true>(v.y); \
            acc[0] += w * f0.x; acc[1] += w * f0.y; \
            acc[2] += w * f1.x; acc[3] += w * f1.y; \
            acc[4] += w * f2.x; acc[5] += w * f2.y; \
            acc[6] += w * f3.x; acc[7] += w * f3.y; }
            ACC8(v0, w0); ACC8(v1, w1); ACC8(v2, w2); ACC8(v3, w3);
#undef ACC8
            if (F == 144) {
                if (ll < 4) {
#define ACCX(xv, w) { \
                    floatx2 e0_ = fp8x2_f32<false>(xv), e1_ = fp8x2_f32<true>(xv); \
                    ex[0] += w * e0_.x; ex[1] += w * e0_.y; \
                    ex[2] += w * e1_.x; ex[3] += w * e1_.y; }
                    ACCX(x0, w0); ACCX(x1, w1); ACCX(x2, w2); ACCX(x3, w3);
#undef ACCX
                }
            }
        }
    }

#pragma unroll
    for (int i = 0; i < 8; i++) {
        acc[i] += __shfl_xor(acc[i], 16);
        acc[i] += __shfl_xor(acc[i], 32);
    }
    if (F == 144) {
#pragma unroll
        for (int i = 0; i < 4; i++) {
            ex[i] += __shfl_xor(ex[i], 16);
            ex[i] += __shfl_xor(ex[i], 32);
        }
    }

    if (g == 0) {
        uint* op = (uint*)T + off_dst + (size_t)node * P;
        const uint* tp = T + off_old + (size_t)node * P;
        if (recur) {
            uint2 ov = ntload_u2((const uint2*)(tp + ll * 2));
            floatx2 f0 = fp8x2_f32<false>(ov.x), f1 = fp8x2_f32<true>(ov.x);
            floatx2 f2 = fp8x2_f32<false>(ov.y), f3 = fp8x2_f32<true>(ov.y);
            acc[0] = 2.f * acc[0] - f0.x; acc[1] = 2.f * acc[1] - f0.y;
            acc[2] = 2.f * acc[2] - f1.x; acc[3] = 2.f * acc[3] - f1.y;
            acc[4] = 2.f * acc[4] - f2.x; acc[5] = 2.f * acc[5] - f2.y;
            acc[6] = 2.f * acc[6] - f3.x; acc[7] = 2.f * acc[7] - f3.y;
            if (F == 144 && ll < 4) {
                uint ox = ntload_u(tp + 32 + ll);
                floatx2 e0_ = fp8x2_f32<false>(ox), e1_ = fp8x2_f32<true>(ox);
                ex[0] = 2.f * ex[0] - e0_.x; ex[1] = 2.f * ex[1] - e0_.y;
                ex[2] = 2.f * ex[2] - e1_.x; ex[3] = 2.f * ex[3] - e1_.y;
            }
        }
        uint2 o;
        o.x = f32_fp8x2<false>(acc[0], acc[1], 0u);
        o.x = f32_fp8x2<true>(acc[2], acc[3], o.x);
        o.y = f32_fp8x2<false>(acc[4], acc[5], 0u);
        o.y = f32_fp8x2<true>(acc[6], acc[7], o.y);
        ntstore_u2((uint2*)(op + ll * 2), o);
        if (F == 144 && ll < 4) {
            uint oe = f32_fp8x2<false>(ex[0], ex[1], 0u);
            oe = f32_fp8x2<true>(ex[2], ex[3], oe);
            ntstore_u(op + 32 + ll, oe);
        }
    }
}

// ---------------------------------------------------------------- MFMA GEMM (pipelined, M-tile 128)
template<int K, bool REDUCE>
__global__ __launch_bounds__(256) void gemm_mfma(const uchar* __restrict__ A,
                                                 const ushort* __restrict__ Bt,
                                                 const float* __restrict__ bias,
                                                 uchar* __restrict__ Cb,
                                                 float* __restrict__ g,
                                                 int M, int CS) {
    __shared__ ushort As[128 * 40];   // 128 rows x 32k bf16, stride 40
    __shared__ ushort Bs[128 * 40];   // 128 cols x 32k bf16, stride 40
    __shared__ float colsum[128];
    int tid = threadIdx.x;
    int m0 = blockIdx.x * 128;
    int lane = tid & 63, wv = tid >> 6;
    int quad = lane >> 4, mrow = lane & 15;

    floatx4 acc[2][8];
#pragma unroll
    for (int mf = 0; mf < 2; mf++)
#pragma unroll
        for (int c = 0; c < 8; c++) acc[mf][c] = (floatx4){0.f, 0.f, 0.f, 0.f};
    if (REDUCE) { if (tid < 128) colsum[tid] = 0.f; }

    int ar = tid >> 1, ak = (tid & 1) * 16;   // A: 16 fp8 per thread
    int bn = tid >> 1, bk = (tid & 1) * 16;   // B: 16 bf16 per thread

    // preload tile 0
    uint4 aReg = make_uint4(0u, 0u, 0u, 0u);
    if (m0 + ar < M) aReg = *(const uint4*)(A + (size_t)(m0 + ar) * K + ak);
    short8 bReg0 = *(const short8*)(Bt + (size_t)bn * K + bk);
    short8 bReg1 = *(const short8*)(Bt + (size_t)bn * K + bk + 8);

    for (int k0 = 0; k0 < K; k0 += 32) {
        floatx2 f0 = fp8x2_f32<false>(aReg.x), f1 = fp8x2_f32<true>(aReg.x);
        floatx2 f2 = fp8x2_f32<false>(aReg.y), f3 = fp8x2_f32<true>(aReg.y);
        floatx2 f4 = fp8x2_f32<false>(aReg.z), f5 = fp8x2_f32<true>(aReg.z);
        floatx2 f6 = fp8x2_f32<false>(aReg.w), f7 = fp8x2_f32<true>(aReg.w);
        uint4 p0, p1;
        p0.x = bf_pack(f0.x, f0.y); p0.y = bf_pack(f1.x, f1.y);
        p0.z = bf_pack(f2.x, f2.y); p0.w = bf_pack(f3.x, f3.y);
        p1.x = bf_pack(f4.x, f4.y); p1.y = bf_pack(f5.x, f5.y);
        p1.z = bf_pack(f6.x, f6.y); p1.w = bf_pack(f7.x, f7.y);
        *(uint4*)(&As[ar * 40 + ak]) = p0;
        *(uint4*)(&As[ar * 40 + ak + 8]) = p1;
        *(short8*)(&Bs[bn * 40 + bk]) = bReg0;
        *(short8*)(&Bs[bn * 40 + bk + 8]) = bReg1;
        __syncthreads();
        int kn = k0 + 32;
        if (kn < K) {
            aReg = make_uint4(0u, 0u, 0u, 0u);
            if (m0 + ar < M) aReg = *(const uint4*)(A + (size_t)(m0 + ar) * K + kn + ak);
            bReg0 = *(const short8*)(Bt + (size_t)bn * K + kn + bk);
            bReg1 = *(const short8*)(Bt + (size_t)bn * K + kn + bk + 8);
        }
        short8 af0 = *(const short8*)(&As[(wv * 32 + mrow) * 40 + quad * 8]);
        short8 af1 = *(const short8*)(&As[(wv * 32 + 16 + mrow) * 40 + quad * 8]);
#pragma unroll
        for (int c = 0; c < 8; c++) {
            short8 bf = *(const short8*)(&Bs[(c * 16 + mrow) * 40 + quad * 8]);
            acc[0][c] = __builtin_amdgcn_mfma_f32_16x16x32_bf16(af0, bf, acc[0][c], 0, 0, 0);
            acc[1][c] = __builtin_amdgcn_mfma_f32_16x16x32_bf16(af1, bf, acc[1][c], 0, 0, 0);
        }
        __syncthreads();
    }

#pragma unroll
    for (int c = 0; c < 8; c++) {
        int col = c * 16 + mrow;
        float bsv = bias[col];
        if (REDUCE) {
            float part = 0.f;
#pragma unroll
            for (int mf = 0; mf < 2; mf++)
#pragma unroll
                for (int r = 0; r < 4; r++) {
                    int row = m0 + wv * 32 + mf * 16 + quad * 4 + r;
                    if (row < M) {
                        float v = acc[mf][c][r] + bsv;
                        part += (v > 0.f) ? v : 0.f;
                    }
                }
            part += __shfl_xor(part, 16);
            part += __shfl_xor(part, 32);
            if (quad == 0) atomicAdd(&colsum[col], part);
        } else {
#pragma unroll
            for (int mf = 0; mf < 2; mf++)
#pragma unroll
                for (int r = 0; r < 4; r++) {
                    int row = m0 + wv * 32 + mf * 16 + quad * 4 + r;
                    if (row < M) {
                        float v = acc[mf][c][r] + bsv;
                        v = (v > 0.f) ? v : 0.f;
                        uint p = f32_fp8x2<false>(v, v, 0u);
                        Cb[(size_t)row * CS + col] = (uchar)(p & 0xFFu);
                    }
                }
        }
    }
    if (REDUCE) {
        __syncthreads();
        if (tid < 128) atomicAdd(&g[tid], colsum[tid]);
    }
}

// ---------------------------------------------------------------- head
__global__ void head_kernel(const float* __restrict__ g,
                            const float* __restrict__ Wmu, const float* __restrict__ bmu,
                            const float* __restrict__ Wlv, const float* __restrict__ blv,
                            float* __restrict__ out, float invN) {
    __shared__ float gm[128];
    int tid = threadIdx.x;
    gm[tid] = g[tid] * invN;
    __syncthreads();
    if (tid < 64) {
        float acc = bmu[tid];
        for (int i = 0; i < 128; i++) acc += gm[i] * Wmu[i * 64 + tid];
        out[tid] = acc;
    } else {
        int j = tid - 64;
        float acc = blv[j];
        for (int i = 0; i < 128; i++) acc += gm[i] * Wlv[i * 64 + j];
        out[64 + j] = acc;
    }
}

// ---------------------------------------------------------------- launch
static inline size_t align64(size_t x) { return (x + 63) & ~(size_t)63; }

extern "C" void kernel_launch(void* const* d_in, const int* in_sizes, int n_in,
                              void* d_out, int out_size, void* d_ws, size_t ws_size,
                              hipStream_t stream) {
    const float* x   = (const float*)d_in[0];
    const int*   ei  = (const int*)d_in[1];
    const float* pe  = (const float*)d_in[2];
    const float* ew  = (const float*)d_in[3];
    const float* W1  = (const float*)d_in[4];
    const float* b1  = (const float*)d_in[5];
    const float* W2  = (const float*)d_in[6];
    const float* b2  = (const float*)d_in[7];
    const float* Wmu = (const float*)d_in[8];
    const float* bmu = (const float*)d_in[9];
    const float* Wlv = (const float*)d_in[10];
    const float* blv = (const float*)d_in[11];
    float* out = (float*)d_out;

    const int N = in_sizes[0] / IN_DIM;
    const int E = in_sizes[3];
    const int NBUCK = (N + 511) >> 9;
    const int NBLK  = (E + 4095) / 4096;
    const int NBLK2 = (E + 2047) / 2048;

    float* ws = (float*)d_ws;
    size_t o_g    = 0;                           // 128
    size_t o_ghA  = o_g + 128;                   // 256
    size_t o_ghB  = o_ghA + 256;                 // 256
    size_t zeroLen = o_ghB + 256;
    size_t o_bbA  = align64(zeroLen);            // 257
    size_t o_curA = align64(o_bbA + 257);        // 256
    size_t o_bbB  = align64(o_curA + 256);       // 257
    size_t o_curB = align64(o_bbB + 257);        // 256
    size_t o_rowp = align64(o_curB + 256);       // N+1
    size_t o_dinv = align64(o_rowp + N + 1);     // N
    size_t o_sA   = align64(o_dinv + N);         // 2E
    size_t o_sB   = align64(o_sA + 2 * (size_t)E);   // 2E
    size_t o_csr  = align64(o_sB + 2 * (size_t)E);   // 2E
    size_t o_Bt1  = align64(o_csr + 2 * (size_t)E);  // 128*576 bf16
    size_t o_Bt2  = align64(o_Bt1 + 128 * 576 / 2);  // 128*512 bf16
    size_t o_T1   = align64(o_Bt2 + 128 * 512 / 2);  // N*144 u32 (4 x 144 fp8)
    size_t o_T2   = align64(o_T1 + (size_t)N * 144); // N*128 u32 (4 x 128 fp8)

    float* g     = ws + o_g;
    int*   ghA   = (int*)(ws + o_ghA);
    int*   ghB   = (int*)(ws + o_ghB);
    int*   bbA   = (int*)(ws + o_bbA);
    int*   curA  = (int*)(ws + o_curA);
    int*   bbB   = (int*)(ws + o_bbB);
    int*   curB  = (int*)(ws + o_curB);
    int*   rowp  = (int*)(ws + o_rowp);
    float* dinv  = ws + o_dinv;
    uint2* sA    = (uint2*)(ws + o_sA);
    uint2* sB    = (uint2*)(ws + o_sB);
    uint2* csr   = (uint2*)(ws + o_csr);
    ushort* Bt1  = (ushort*)(ws + o_Bt1);
    ushort* Bt2  = (ushort*)(ws + o_Bt2);
    uint*  T1    = (uint*)(ws + o_T1);
    uint*  T2    = (uint*)(ws + o_T2);

    dim3 b256(256);

    // ---- graph prep
    zero_kernel<<<dim3((unsigned)((zeroLen + 255) / 256)), b256, 0, stream>>>(ws, zeroLen);
    bin_hist<<<dim3(NBLK), b256, 0, stream>>>(ei, ghA, ghB, E);
    bin_scan<<<dim3(1), b256, 0, stream>>>(ghA, ghB, bbA, curA, bbB, curB);
    bin_scatter2<<<dim3(NBLK2), b256, 0, stream>>>(ei, ew, curA, curB, sA, sB, E);
    deg_bucket<<<dim3(NBUCK), b256, 0, stream>>>(sA, bbA, dinv, N);
    csr_bucket<<<dim3(NBUCK), b256, 0, stream>>>(sB, bbB, dinv, rowp, csr, N, NBUCK, E);

    // ---- weights -> bf16 transposed
    wconv_kernel<576><<<dim3((128 * 576 + 255) / 256), b256, 0, stream>>>(W1, Bt1);
    wconv_kernel<512><<<dim3((128 * 512 + 255) / 256), b256, 0, stream>>>(W2, Bt2);

    // ---- T1 slice 0 = [x, pe] in fp8
    concat_x_fp8<<<dim3((unsigned)(((size_t)N * 32 + 255) / 256)), b256, 0, stream>>>(x, T1, (size_t)N * 32);
    concat_pe_fp8<<<dim3((unsigned)(((size_t)N * 4 + 255) / 256)), b256, 0, stream>>>(pe, T1, (size_t)N * 4);

    const unsigned propGrid = (unsigned)((N + 3) / 4);
    const unsigned gemmGrid = (unsigned)((N + 127) / 128);

    // ---- layer 1: T1 row stride 144 uints, slices at k*36
    prop_fp8<144, 144><<<propGrid, b256, 0, stream>>>(T1, 0,  36,  0,  0, rowp, csr, N);
    prop_fp8<144, 144><<<propGrid, b256, 0, stream>>>(T1, 36, 72,  0,  1, rowp, csr, N);
    prop_fp8<144, 144><<<propGrid, b256, 0, stream>>>(T1, 72, 108, 36, 1, rowp, csr, N);
    gemm_mfma<576, false><<<gemmGrid, b256, 0, stream>>>((const uchar*)T1, Bt1, b1, (uchar*)T2, g, N, 512);

    // ---- layer 2: T2 row stride 128 uints, slices at k*32
    prop_fp8<128, 128><<<propGrid, b256, 0, stream>>>(T2, 0,  32, 0,  0, rowp, csr, N);
    prop_fp8<128, 128><<<propGrid, b256, 0, stream>>>(T2, 32, 64, 0,  1, rowp, csr, N);
    prop_fp8<128, 128><<<propGrid, b256, 0, stream>>>(T2, 64, 96, 32, 1, rowp, csr, N);
    gemm_mfma<512, true><<<gemmGrid, b256, 0, stream>>>((const uchar*)T2, Bt2, b2, (uchar*)nullptr, g, N, 0);

    // ---- heads
    head_kernel<<<dim3(1), dim3(128), 0, stream>>>(g, Wmu, bmu, Wlv, blv, out, 1.0f / (float)N);
}

// Round 11
// 622.155 us; speedup vs baseline: 1.1137x; 1.1137x over previous
//
#include <hip/hip_runtime.h>
#include <hip/hip_bf16.h>

#define IN_DIM 128
#define PE_DIM 16
#define F_IN 144      // IN+PE
#define HID 128
#define LAT 64
#define K_CHEB 4

typedef unsigned int uint;
typedef unsigned short ushort;
typedef unsigned char uchar;
typedef __attribute__((ext_vector_type(8))) short short8;
typedef __attribute__((ext_vector_type(4))) float floatx4;
typedef __attribute__((ext_vector_type(2))) float floatx2;

// ---------------------------------------------------------------- bf16 helpers
__device__ __forceinline__ ushort f2bf(float f) {
    uint u = __float_as_uint(f);
    uint r = (u + 0x7FFFu + ((u >> 16) & 1u)) >> 16;   // RNE
    return (ushort)r;
}
__device__ __forceinline__ uint bf_pack(float lo, float hi) {
    return (uint)f2bf(lo) | ((uint)f2bf(hi) << 16);
}

// ---------------------------------------------------------------- fp8 helpers (OCP e4m3 on gfx950)
template<bool HI>
__device__ __forceinline__ floatx2 fp8x2_f32(uint v) {
    return __builtin_amdgcn_cvt_pk_f32_fp8((int)v, HI);
}
template<bool HI>
__device__ __forceinline__ uint f32_fp8x2(float a, float b, uint old) {
    return (uint)__builtin_amdgcn_cvt_pk_fp8_f32(a, b, (int)old, HI);
}

// ---------------------------------------------------------------- utility
__global__ void zero_kernel(float* __restrict__ p, size_t n) {
    size_t i = (size_t)blockIdx.x * 256 + threadIdx.x;
    if (i < n) p[i] = 0.f;
}

// ================================================================ graph prep
// 512-node buckets; NBUCK = ceil(N/512) <= 256.

__global__ __launch_bounds__(256) void bin_hist(const int* __restrict__ ei,
                                                int* __restrict__ ghA,
                                                int* __restrict__ ghB, int E) {
    __shared__ int hA[256], hB[256];
    int t = threadIdx.x;
    hA[t] = 0; hB[t] = 0;
    __syncthreads();
    int base = blockIdx.x * 4096;
#pragma unroll
    for (int j = 0; j < 16; j++) {
        int e = base + t + j * 256;
        if (e < E) {
            int s = ei[e], d = ei[E + e];
            atomicAdd(&hA[s >> 9], 1);
            atomicAdd(&hB[d >> 9], 1);
        }
    }
    __syncthreads();
    atomicAdd(&ghA[t], hA[t]);
    atomicAdd(&ghB[t], hB[t]);
}

__global__ __launch_bounds__(256) void bin_scan(const int* __restrict__ ghA,
                                                const int* __restrict__ ghB,
                                                int* __restrict__ bbA, int* __restrict__ curA,
                                                int* __restrict__ bbB, int* __restrict__ curB) {
    __shared__ int s[256];
    int t = threadIdx.x;
    int v = ghA[t];
    s[t] = v; __syncthreads();
    for (int off = 1; off < 256; off <<= 1) {
        int u = (t >= off) ? s[t - off] : 0;
        __syncthreads(); s[t] += u; __syncthreads();
    }
    bbA[t] = s[t] - v; curA[t] = s[t] - v;
    if (t == 255) bbA[256] = s[255];
    __syncthreads();
    int v2 = ghB[t];
    s[t] = v2; __syncthreads();
    for (int off = 1; off < 256; off <<= 1) {
        int u = (t >= off) ? s[t - off] : 0;
        __syncthreads(); s[t] += u; __syncthreads();
    }
    bbB[t] = s[t] - v2; curB[t] = s[t] - v2;
    if (t == 255) bbB[256] = s[255];
}

// ---- dual scatter: one pass over edges builds BOTH bucket-grouped streams.
// A: key=src, rec=(src, w).  B: key=dst, rec=(src | dstLow<<17, w).
__global__ __launch_bounds__(256) void bin_scatter2(const int* __restrict__ ei,
                                                    const float* __restrict__ ew,
                                                    int* __restrict__ curA,
                                                    int* __restrict__ curB,
                                                    uint2* __restrict__ sA,
                                                    uint2* __restrict__ sB, int E) {
    __shared__ uint2 recA[2048]; __shared__ int posA[2048];
    __shared__ uint2 recB[2048]; __shared__ int posB[2048];
    __shared__ int hstA[256], scnA[256], runA[256], bgA[256];
    __shared__ int hstB[256], scnB[256], runB[256], bgB[256];
    int t = threadIdx.x;
    hstA[t] = 0; hstB[t] = 0;
    __syncthreads();
    int base = blockIdx.x * 2048;
    int cntBlk = E - base; if (cntBlk > 2048) cntBlk = 2048;
    int sv[8], dv[8]; float wv[8];
#pragma unroll
    for (int j = 0; j < 8; j++) {
        int e = base + t + j * 256;
        if (e < E) {
            sv[j] = ei[e]; dv[j] = ei[E + e];
            wv[j] = (sv[j] == dv[j]) ? 0.f : ew[e];
            atomicAdd(&hstA[sv[j] >> 9], 1);
            atomicAdd(&hstB[dv[j] >> 9], 1);
        } else sv[j] = -1;
    }
    __syncthreads();
    // scan A
    int vA = hstA[t];
    scnA[t] = vA; __syncthreads();
    for (int off = 1; off < 256; off <<= 1) {
        int u = (t >= off) ? scnA[t - off] : 0;
        __syncthreads(); scnA[t] += u; __syncthreads();
    }
    int eA = scnA[t] - vA;
    bgA[t] = atomicAdd(&curA[t], vA);
    __syncthreads();
    scnA[t] = eA; runA[t] = eA;
    // scan B
    int vB = hstB[t];
    scnB[t] = vB; __syncthreads();
    for (int off = 1; off < 256; off <<= 1) {
        int u = (t >= off) ? scnB[t - off] : 0;
        __syncthreads(); scnB[t] += u; __syncthreads();
    }
    int eB = scnB[t] - vB;
    bgB[t] = atomicAdd(&curB[t], vB);
    __syncthreads();
    scnB[t] = eB; runB[t] = eB;
    __syncthreads();
#pragma unroll
    for (int j = 0; j < 8; j++) {
        if (sv[j] >= 0) {
            int bA = sv[j] >> 9;
            int slot = atomicAdd(&runA[bA], 1);
            uint2 r; r.x = (uint)sv[j]; r.y = __float_as_uint(wv[j]);
            recA[slot] = r;
            posA[slot] = bgA[bA] + (slot - scnA[bA]);
            int bB = dv[j] >> 9;
            int slot2 = atomicAdd(&runB[bB], 1);
            uint2 r2; r2.x = (uint)sv[j] | ((uint)(dv[j] & 511) << 17); r2.y = __float_as_uint(wv[j]);
            recB[slot2] = r2;
            posB[slot2] = bgB[bB] + (slot2 - scnB[bB]);
        }
    }
    __syncthreads();
    for (int i = t; i < cntBlk; i += 256) {
        sA[posA[i]] = recA[i];
        sB[posB[i]] = recB[i];
    }
}

__global__ __launch_bounds__(256) void deg_bucket(const uint2* __restrict__ sA,
                                                  const int* __restrict__ bbA,
                                                  float* __restrict__ dinv, int N) {
    __shared__ float dl[512];
    int b = blockIdx.x, t = threadIdx.x;
    dl[t] = 0.f; dl[t + 256] = 0.f;
    __syncthreads();
    int s0 = bbA[b], s1 = bbA[b + 1];
    for (int r = s0 + t; r < s1; r += 256) {
        uint2 rc = sA[r];
        atomicAdd(&dl[(int)rc.x - (b << 9)], __uint_as_float(rc.y));
    }
    __syncthreads();
    for (int i = t; i < 512; i += 256) {
        int node = (b << 9) + i;
        if (node < N) {
            float d = dl[i];
            dinv[node] = (d > 0.f) ? rsqrtf(d) : 0.f;
        }
    }
}

__global__ __launch_bounds__(256) void csr_bucket(const uint2* __restrict__ sB,
                                                  const int* __restrict__ bbB,
                                                  const float* __restrict__ dinv,
                                                  int* __restrict__ rowp,
                                                  uint2* __restrict__ csr,
                                                  int N, int nbuck, int E) {
    __shared__ int cl[512], ol[512], orun[512];
    __shared__ float dvl[512];
    __shared__ int ps[256];
    int b = blockIdx.x, t = threadIdx.x;
    cl[t] = 0; cl[t + 256] = 0;
    for (int i = t; i < 512; i += 256) {
        int node = (b << 9) + i;
        dvl[i] = (node < N) ? dinv[node] : 0.f;
    }
    __syncthreads();
    int s0 = bbB[b], s1 = bbB[b + 1];
    for (int r = s0 + t; r < s1; r += 256)
        atomicAdd(&cl[(sB[r].x >> 17) & 511], 1);
    __syncthreads();
    int v0 = cl[2 * t], v1 = cl[2 * t + 1];
    int pv = v0 + v1;
    ps[t] = pv; __syncthreads();
    for (int off = 1; off < 256; off <<= 1) {
        int u = (t >= off) ? ps[t - off] : 0;
        __syncthreads(); ps[t] += u; __syncthreads();
    }
    int pexcl = ps[t] - pv;
    ol[2 * t] = pexcl;       ol[2 * t + 1] = pexcl + v0;
    orun[2 * t] = pexcl;     orun[2 * t + 1] = pexcl + v0;
    {
        int n0 = (b << 9) + 2 * t;
        if (n0 < N)     rowp[n0] = s0 + ol[2 * t];
        if (n0 + 1 < N) rowp[n0 + 1] = s0 + ol[2 * t + 1];
    }
    if (b == nbuck - 1 && t == 0) rowp[N] = E;
    __syncthreads();
    for (int r = s0 + t; r < s1; r += 256) {
        uint2 rc = sB[r];
        int src = rc.x & 0x1FFFF;
        int dl_ = (rc.x >> 17) & 511;
        float w = __uint_as_float(rc.y);
        int rank = atomicAdd(&orun[dl_], 1);
        float wh = -dinv[src] * w * dvl[dl_];
        uint2 o; o.x = (uint)src; o.y = __float_as_uint(wh);
        csr[s0 + rank] = o;
    }
}

// ---------------------------------------------------------------- concat -> fp8 T1 slice 0
// T1 row = 4 slices x 144 fp8 = 576 B = 144 uints; slice0 uints [0,36)
__global__ void concat_x_fp8(const float* __restrict__ x, uint* __restrict__ T, size_t np) {
    size_t idx = (size_t)blockIdx.x * 256 + threadIdx.x;
    if (idx >= np) return;
    size_t i = idx >> 5; int p = (int)(idx & 31);
    float4 v = *(const float4*)(x + i * 128 + p * 4);
    uint o = f32_fp8x2<false>(v.x, v.y, 0u);
    o = f32_fp8x2<true>(v.z, v.w, o);
    T[i * 144 + p] = o;
}
__global__ void concat_pe_fp8(const float* __restrict__ pe, uint* __restrict__ T, size_t np) {
    size_t idx = (size_t)blockIdx.x * 256 + threadIdx.x;
    if (idx >= np) return;
    size_t i = idx >> 2; int p = (int)(idx & 3);
    float4 v = *(const float4*)(pe + i * 16 + p * 4);
    uint o = f32_fp8x2<false>(v.x, v.y, 0u);
    o = f32_fp8x2<true>(v.z, v.w, o);
    T[i * 144 + 32 + p] = o;
}

// ---------------------------------------------------------------- W -> Bt bf16 transpose (weights stay bf16)
template<int K>
__global__ void wconv_kernel(const float* __restrict__ W, ushort* __restrict__ Bt) {
    int idx = blockIdx.x * 256 + threadIdx.x;
    if (idx >= 128 * K) return;
    int n = idx / K, kk = idx - n * K;
    Bt[idx] = f2bf(W[(size_t)kk * 128 + n]);
}

// ---------------------------------------------------------------- propagate (fp8 tables, fp32 accum)
// One wave per node; 4 edge-groups x 16 lanes; 16 edges per iteration, uint2
// (8 fp8) per lane per edge. Plain loads/stores (nt hints measured harmful on
// gfx950 — R10: 64.4 -> 71.6 us with FETCH unchanged).
template<int F, int P>
__global__ __launch_bounds__(256) void prop_fp8(const uint* __restrict__ T,
                                                int off_src, int off_dst, int off_old,
                                                int recur,
                                                const int* __restrict__ rowp,
                                                const uint2* __restrict__ csrE, int n) {
    int node = blockIdx.x * 4 + (threadIdx.x >> 6);
    if (node >= n) return;
    int lane = threadIdx.x & 63;
    int g = lane >> 4;          // edge sub-group 0..3
    int ll = lane & 15;         // lane within group
    int e0 = rowp[node], e1 = rowp[node + 1];

    const uint* Tsrc = T + off_src;

    float acc[8];
#pragma unroll
    for (int i = 0; i < 8; i++) acc[i] = 0.f;
    float ex[4] = {0.f, 0.f, 0.f, 0.f};

    for (int base = e0; base < e1; base += 64) {
        int degc = e1 - base; if (degc > 64) degc = 64;
        int sidx = 0; float wval = 0.f;
        if (lane < degc) {
            uint2 rc = csrE[base + lane];
            sidx = (int)rc.x; wval = __uint_as_float(rc.y);
        }
        for (int j = 0; j < degc; j += 16) {
            int j0 = j + g, j1 = j0 + 4, j2 = j0 + 8, j3 = j0 + 12;
            int   s0 = __shfl(sidx, j0), s1 = __shfl(sidx, j1);
            int   s2 = __shfl(sidx, j2), s3 = __shfl(sidx, j3);
            float w0 = __shfl(wval, j0), w1 = __shfl(wval, j1);
            float w2 = __shfl(wval, j2), w3 = __shfl(wval, j3);
            const uint* hp0 = Tsrc + (size_t)s0 * P;
            const uint* hp1 = Tsrc + (size_t)s1 * P;
            const uint* hp2 = Tsrc + (size_t)s2 * P;
            const uint* hp3 = Tsrc + (size_t)s3 * P;
            uint2 v0 = *(const uint2*)(hp0 + ll * 2);
            uint2 v1 = *(const uint2*)(hp1 + ll * 2);
            uint2 v2 = *(const uint2*)(hp2 + ll * 2);
            uint2 v3 = *(const uint2*)(hp3 + ll * 2);
            uint x0 = 0, x1 = 0, x2 = 0, x3 = 0;
            if (F == 144) {
                if (ll < 4) {
                    x0 = hp0[32 + ll]; x1 = hp1[32 + ll];
                    x2 = hp2[32 + ll]; x3 = hp3[32 + ll];
                }
            }
#define ACC8(v, w) { \
            floatx2 f0 = fp8x2_f32<false>(v.x), f1 = fp8x2_f32<true>(v.x); \
            floatx2 f2 = fp8x2_f32<false>(v.y), f3 = fp8x2_f32<true>(v.y); \
            acc[0] += w * f0.x; acc[1] += w * f0.y; \
            acc[2] += w * f1.x; acc[3] += w * f1.y; \
            acc[4] += w * f2.x; acc[5] += w * f2.y; \
            acc[6] += w * f3.x; acc[7] += w * f3.y; }
            ACC8(v0, w0); ACC8(v1, w1); ACC8(v2, w2); ACC8(v3, w3);
#undef ACC8
            if (F == 144) {
                if (ll < 4) {
#define ACCX(xv, w) { \
                    floatx2 e0_ = fp8x2_f32<false>(xv), e1_ = fp8x2_f32<true>(xv); \
                    ex[0] += w * e0_.x; ex[1] += w * e0_.y; \
                    ex[2] += w * e1_.x; ex[3] += w * e1_.y; }
                    ACCX(x0, w0); ACCX(x1, w1); ACCX(x2, w2); ACCX(x3, w3);
#undef ACCX
                }
            }
        }
    }

#pragma unroll
    for (int i = 0; i < 8; i++) {
        acc[i] += __shfl_xor(acc[i], 16);
        acc[i] += __shfl_xor(acc[i], 32);
    }
    if (F == 144) {
#pragma unroll
        for (int i = 0; i < 4; i++) {
            ex[i] += __shfl_xor(ex[i], 16);
            ex[i] += __shfl_xor(ex[i], 32);
        }
    }

    if (g == 0) {
        uint* op = (uint*)T + off_dst + (size_t)node * P;
        const uint* tp = T + off_old + (size_t)node * P;
        if (recur) {
            uint2 ov = *(const uint2*)(tp + ll * 2);
            floatx2 f0 = fp8x2_f32<false>(ov.x), f1 = fp8x2_f32<true>(ov.x);
            floatx2 f2 = fp8x2_f32<false>(ov.y), f3 = fp8x2_f32<true>(ov.y);
            acc[0] = 2.f * acc[0] - f0.x; acc[1] = 2.f * acc[1] - f0.y;
            acc[2] = 2.f * acc[2] - f1.x; acc[3] = 2.f * acc[3] - f1.y;
            acc[4] = 2.f * acc[4] - f2.x; acc[5] = 2.f * acc[5] - f2.y;
            acc[6] = 2.f * acc[6] - f3.x; acc[7] = 2.f * acc[7] - f3.y;
            if (F == 144 && ll < 4) {
                uint ox = tp[32 + ll];
                floatx2 e0_ = fp8x2_f32<false>(ox), e1_ = fp8x2_f32<true>(ox);
                ex[0] = 2.f * ex[0] - e0_.x; ex[1] = 2.f * ex[1] - e0_.y;
                ex[2] = 2.f * ex[2] - e1_.x; ex[3] = 2.f * ex[3] - e1_.y;
            }
        }
        uint2 o;
        o.x = f32_fp8x2<false>(acc[0], acc[1], 0u);
        o.x = f32_fp8x2<true>(acc[2], acc[3], o.x);
        o.y = f32_fp8x2<false>(acc[4], acc[5], 0u);
        o.y = f32_fp8x2<true>(acc[6], acc[7], o.y);
        *(uint2*)(op + ll * 2) = o;
        if (F == 144 && ll < 4) {
            uint oe = f32_fp8x2<false>(ex[0], ex[1], 0u);
            oe = f32_fp8x2<true>(ex[2], ex[3], oe);
            op[32 + ll] = oe;
        }
    }
}

// ---------------------------------------------------------------- MFMA GEMM (pipelined, M-tile 128)
template<int K, bool REDUCE>
__global__ __launch_bounds__(256) void gemm_mfma(const uchar* __restrict__ A,
                                                 const ushort* __restrict__ Bt,
                                                 const float* __restrict__ bias,
                                                 uchar* __restrict__ Cb,
                                                 float* __restrict__ g,
                                                 int M, int CS) {
    __shared__ ushort As[128 * 40];   // 128 rows x 32k bf16, stride 40
    __shared__ ushort Bs[128 * 40];   // 128 cols x 32k bf16, stride 40
    __shared__ float colsum[128];
    int tid = threadIdx.x;
    int m0 = blockIdx.x * 128;
    int lane = tid & 63, wv = tid >> 6;
    int quad = lane >> 4, mrow = lane & 15;

    floatx4 acc[2][8];
#pragma unroll
    for (int mf = 0; mf < 2; mf++)
#pragma unroll
        for (int c = 0; c < 8; c++) acc[mf][c] = (floatx4){0.f, 0.f, 0.f, 0.f};
    if (REDUCE) { if (tid < 128) colsum[tid] = 0.f; }

    int ar = tid >> 1, ak = (tid & 1) * 16;   // A: 16 fp8 per thread
    int bn = tid >> 1, bk = (tid & 1) * 16;   // B: 16 bf16 per thread

    // preload tile 0
    uint4 aReg = make_uint4(0u, 0u, 0u, 0u);
    if (m0 + ar < M) aReg = *(const uint4*)(A + (size_t)(m0 + ar) * K + ak);
    short8 bReg0 = *(const short8*)(Bt + (size_t)bn * K + bk);
    short8 bReg1 = *(const short8*)(Bt + (size_t)bn * K + bk + 8);

    for (int k0 = 0; k0 < K; k0 += 32) {
        floatx2 f0 = fp8x2_f32<false>(aReg.x), f1 = fp8x2_f32<true>(aReg.x);
        floatx2 f2 = fp8x2_f32<false>(aReg.y), f3 = fp8x2_f32<true>(aReg.y);
        floatx2 f4 = fp8x2_f32<false>(aReg.z), f5 = fp8x2_f32<true>(aReg.z);
        floatx2 f6 = fp8x2_f32<false>(aReg.w), f7 = fp8x2_f32<true>(aReg.w);
        uint4 p0, p1;
        p0.x = bf_pack(f0.x, f0.y); p0.y = bf_pack(f1.x, f1.y);
        p0.z = bf_pack(f2.x, f2.y); p0.w = bf_pack(f3.x, f3.y);
        p1.x = bf_pack(f4.x, f4.y); p1.y = bf_pack(f5.x, f5.y);
        p1.z = bf_pack(f6.x, f6.y); p1.w = bf_pack(f7.x, f7.y);
        *(uint4*)(&As[ar * 40 + ak]) = p0;
        *(uint4*)(&As[ar * 40 + ak + 8]) = p1;
        *(short8*)(&Bs[bn * 40 + bk]) = bReg0;
        *(short8*)(&Bs[bn * 40 + bk + 8]) = bReg1;
        __syncthreads();
        int kn = k0 + 32;
        if (kn < K) {
            aReg = make_uint4(0u, 0u, 0u, 0u);
            if (m0 + ar < M) aReg = *(const uint4*)(A + (size_t)(m0 + ar) * K + kn + ak);
            bReg0 = *(const short8*)(Bt + (size_t)bn * K + kn + bk);
            bReg1 = *(const short8*)(Bt + (size_t)bn * K + kn + bk + 8);
        }
        short8 af0 = *(const short8*)(&As[(wv * 32 + mrow) * 40 + quad * 8]);
        short8 af1 = *(const short8*)(&As[(wv * 32 + 16 + mrow) * 40 + quad * 8]);
#pragma unroll
        for (int c = 0; c < 8; c++) {
            short8 bf = *(const short8*)(&Bs[(c * 16 + mrow) * 40 + quad * 8]);
            acc[0][c] = __builtin_amdgcn_mfma_f32_16x16x32_bf16(af0, bf, acc[0][c], 0, 0, 0);
            acc[1][c] = __builtin_amdgcn_mfma_f32_16x16x32_bf16(af1, bf, acc[1][c], 0, 0, 0);
        }
        __syncthreads();
    }

#pragma unroll
    for (int c = 0; c < 8; c++) {
        int col = c * 16 + mrow;
        float bsv = bias[col];
        if (REDUCE) {
            float part = 0.f;
#pragma unroll
            for (int mf = 0; mf < 2; mf++)
#pragma unroll
                for (int r = 0; r < 4; r++) {
                    int row = m0 + wv * 32 + mf * 16 + quad * 4 + r;
                    if (row < M) {
                        float v = acc[mf][c][r] + bsv;
                        part += (v > 0.f) ? v : 0.f;
                    }
                }
            part += __shfl_xor(part, 16);
            part += __shfl_xor(part, 32);
            if (quad == 0) atomicAdd(&colsum[col], part);
        } else {
#pragma unroll
            for (int mf = 0; mf < 2; mf++)
#pragma unroll
                for (int r = 0; r < 4; r++) {
                    int row = m0 + wv * 32 + mf * 16 + quad * 4 + r;
                    if (row < M) {
                        float v = acc[mf][c][r] + bsv;
                        v = (v > 0.f) ? v : 0.f;
                        uint p = f32_fp8x2<false>(v, v, 0u);
                        Cb[(size_t)row * CS + col] = (uchar)(p & 0xFFu);
                    }
                }
        }
    }
    if (REDUCE) {
        __syncthreads();
        if (tid < 128) atomicAdd(&g[tid], colsum[tid]);
    }
}

// ---------------------------------------------------------------- head
__global__ void head_kernel(const float* __restrict__ g,
                            const float* __restrict__ Wmu, const float* __restrict__ bmu,
                            const float* __restrict__ Wlv, const float* __restrict__ blv,
                            float* __restrict__ out, float invN) {
    __shared__ float gm[128];
    int tid = threadIdx.x;
    gm[tid] = g[tid] * invN;
    __syncthreads();
    if (tid < 64) {
        float acc = bmu[tid];
        for (int i = 0; i < 128; i++) acc += gm[i] * Wmu[i * 64 + tid];
        out[tid] = acc;
    } else {
        int j = tid - 64;
        float acc = blv[j];
        for (int i = 0; i < 128; i++) acc += gm[i] * Wlv[i * 64 + j];
        out[64 + j] = acc;
    }
}

// ---------------------------------------------------------------- launch
static inline size_t align64(size_t x) { return (x + 63) & ~(size_t)63; }

extern "C" void kernel_launch(void* const* d_in, const int* in_sizes, int n_in,
                              void* d_out, int out_size, void* d_ws, size_t ws_size,
                              hipStream_t stream) {
    const float* x   = (const float*)d_in[0];
    const int*   ei  = (const int*)d_in[1];
    const float* pe  = (const float*)d_in[2];
    const float* ew  = (const float*)d_in[3];
    const float* W1  = (const float*)d_in[4];
    const float* b1  = (const float*)d_in[5];
    const float* W2  = (const float*)d_in[6];
    const float* b2  = (const float*)d_in[7];
    const float* Wmu = (const float*)d_in[8];
    const float* bmu = (const float*)d_in[9];
    const float* Wlv = (const float*)d_in[10];
    const float* blv = (const float*)d_in[11];
    float* out = (float*)d_out;

    const int N = in_sizes[0] / IN_DIM;
    const int E = in_sizes[3];
    const int NBUCK = (N + 511) >> 9;
    const int NBLK  = (E + 4095) / 4096;
    const int NBLK2 = (E + 2047) / 2048;

    float* ws = (float*)d_ws;
    size_t o_g    = 0;                           // 128
    size_t o_ghA  = o_g + 128;                   // 256
    size_t o_ghB  = o_ghA + 256;                 // 256
    size_t zeroLen = o_ghB + 256;
    size_t o_bbA  = align64(zeroLen);            // 257
    size_t o_curA = align64(o_bbA + 257);        // 256
    size_t o_bbB  = align64(o_curA + 256);       // 257
    size_t o_curB = align64(o_bbB + 257);        // 256
    size_t o_rowp = align64(o_curB + 256);       // N+1
    size_t o_dinv = align64(o_rowp + N + 1);     // N
    size_t o_sA   = align64(o_dinv + N);         // 2E
    size_t o_sB   = align64(o_sA + 2 * (size_t)E);   // 2E
    size_t o_csr  = align64(o_sB + 2 * (size_t)E);   // 2E
    size_t o_Bt1  = align64(o_csr + 2 * (size_t)E);  // 128*576 bf16
    size_t o_Bt2  = align64(o_Bt1 + 128 * 576 / 2);  // 128*512 bf16
    size_t o_T1   = align64(o_Bt2 + 128 * 512 / 2);  // N*144 u32 (4 x 144 fp8)
    size_t o_T2   = align64(o_T1 + (size_t)N * 144); // N*128 u32 (4 x 128 fp8)

    float* g     = ws + o_g;
    int*   ghA   = (int*)(ws + o_ghA);
    int*   ghB   = (int*)(ws + o_ghB);
    int*   bbA   = (int*)(ws + o_bbA);
    int*   curA  = (int*)(ws + o_curA);
    int*   bbB   = (int*)(ws + o_bbB);
    int*   curB  = (int*)(ws + o_curB);
    int*   rowp  = (int*)(ws + o_rowp);
    float* dinv  = ws + o_dinv;
    uint2* sA    = (uint2*)(ws + o_sA);
    uint2* sB    = (uint2*)(ws + o_sB);
    uint2* csr   = (uint2*)(ws + o_csr);
    ushort* Bt1  = (ushort*)(ws + o_Bt1);
    ushort* Bt2  = (ushort*)(ws + o_Bt2);
    uint*  T1    = (uint*)(ws + o_T1);
    uint*  T2    = (uint*)(ws + o_T2);

    dim3 b256(256);

    // ---- graph prep
    zero_kernel<<<dim3((unsigned)((zeroLen + 255) / 256)), b256, 0, stream>>>(ws, zeroLen);
    bin_hist<<<dim3(NBLK), b256, 0, stream>>>(ei, ghA, ghB, E);
    bin_scan<<<dim3(1), b256, 0, stream>>>(ghA, ghB, bbA, curA, bbB, curB);
    bin_scatter2<<<dim3(NBLK2), b256, 0, stream>>>(ei, ew, curA, curB, sA, sB, E);
    deg_bucket<<<dim3(NBUCK), b256, 0, stream>>>(sA, bbA, dinv, N);
    csr_bucket<<<dim3(NBUCK), b256, 0, stream>>>(sB, bbB, dinv, rowp, csr, N, NBUCK, E);

    // ---- weights -> bf16 transposed
    wconv_kernel<576><<<dim3((128 * 576 + 255) / 256), b256, 0, stream>>>(W1, Bt1);
    wconv_kernel<512><<<dim3((128 * 512 + 255) / 256), b256, 0, stream>>>(W2, Bt2);

    // ---- T1 slice 0 = [x, pe] in fp8
    concat_x_fp8<<<dim3((unsigned)(((size_t)N * 32 + 255) / 256)), b256, 0, stream>>>(x, T1, (size_t)N * 32);
    concat_pe_fp8<<<dim3((unsigned)(((size_t)N * 4 + 255) / 256)), b256, 0, stream>>>(pe, T1, (size_t)N * 4);

    const unsigned propGrid = (unsigned)((N + 3) / 4);
    const unsigned gemmGrid = (unsigned)((N + 127) / 128);

    // ---- layer 1: T1 row stride 144 uints, slices at k*36
    prop_fp8<144, 144><<<propGrid, b256, 0, stream>>>(T1, 0,  36,  0,  0, rowp, csr, N);
    prop_fp8<144, 144><<<propGrid, b256, 0, stream>>>(T1, 36, 72,  0,  1, rowp, csr, N);
    prop_fp8<144, 144><<<propGrid, b256, 0, stream>>>(T1, 72, 108, 36, 1, rowp, csr, N);
    gemm_mfma<576, false><<<gemmGrid, b256, 0, stream>>>((const uchar*)T1, Bt1, b1, (uchar*)T2, g, N, 512);

    // ---- layer 2: T2 row stride 128 uints, slices at k*32
    prop_fp8<128, 128><<<propGrid, b256, 0, stream>>>(T2, 0,  32, 0,  0, rowp, csr, N);
    prop_fp8<128, 128><<<propGrid, b256, 0, stream>>>(T2, 32, 64, 0,  1, rowp, csr, N);
    prop_fp8<128, 128><<<propGrid, b256, 0, stream>>>(T2, 64, 96, 32, 1, rowp, csr, N);
    gemm_mfma<512, true><<<gemmGrid, b256, 0, stream>>>((const uchar*)T2, Bt2, b2, (uchar*)nullptr, g, N, 0);

    // ---- heads
    head_kernel<<<dim3(1), dim3(128), 0, stream>>>(g, Wmu, bmu, Wlv, blv, out, 1.0f / (float)N);
}